// Round 4
// baseline (3499.187 us; speedup 1.0000x reference)
//
#include <hip/hip_runtime.h>
#include <math.h>

// ChamferLoss on MI355X — round 2 kernel (3rd submit; rounds 2-3 were infra
// failures, never measured).
// P = transform(tar), Q = transform(fake).
// Dot-product form: d(p,q) = 2*(hp + hq - p.q), h = 0.5*|.|^2 precomputed.
// Row chain accumulates min_j (hq_j - t); col chain min_i (hp_i - t); both
// lane-private via the ring-rotation trick. Final: dist1 = 2*(hp + rowmin),
// dist2 = 2*(hq + colmin). Signed floats -> monotonic uint map for atomicMin.

#define N_PTS 147456   // 384*384
#define IMG_W 384
#define RI 8           // rows per lane
#define RJ 8           // cols per lane
#define TROWS 512      // RI*64  (wave tile rows)
#define TCOLS 512      // RJ*64  (wave tile cols)
#define STRIP 4        // col-tiles per wave job (amortizes row atomics)
#define NBAND  (N_PTS / TROWS)           // 288
#define NSTRIP (N_PTS / (TCOLS * STRIP)) // 72
#define NJOBS  (NBAND * NSTRIP)          // 20736 waves -> 5184 blocks

__device__ __forceinline__ float min3f(float a, float b, float c) {
    float r;
    asm("v_min3_f32 %0, %1, %2, %3" : "=v"(r) : "v"(a), "v"(b), "v"(c));
    return r;
}

// monotonic float->uint map: uint order == float order (handles negatives)
__device__ __forceinline__ unsigned encf(float f) {
    unsigned u = __float_as_uint(f);
    return (u & 0x80000000u) ? ~u : (u | 0x80000000u);
}
__device__ __forceinline__ float decf(unsigned k) {
    return __uint_as_float((k & 0x80000000u) ? (k ^ 0x80000000u) : ~k);
}

// depth -> (x,y,z, 0.5*|xyz|^2) for both clouds; init min buffers.
__global__ __launch_bounds__(256) void prep_kernel(
    const float* __restrict__ fake, const float* __restrict__ tar,
    const int* __restrict__ sh_p, const int* __restrict__ sw_p,
    float4* __restrict__ A, float4* __restrict__ B,
    unsigned* __restrict__ minbuf)
{
    int idx = blockIdx.x * 256 + threadIdx.x;
    if (idx >= N_PTS) return;
    int r = idx / IMG_W, c = idx - r * IMG_W;
    int sh = *sh_p, sw = *sw_p;
    float cw = (float)((double)sw / 1285.0 * 360.0);
    float ch = (float)((double)sh / 438.0 * 123.5);
    const float fh = (float)(360.0 * 384.0 / 1285.0);   // fh_crop
    const float fv = (float)(123.5 * 384.0 / 438.0);    // fv_crop
    const float D2R = 0.017453292519943295f;
    float yaw = ((-fh * (float)c) / 384.0f + cw) * D2R;
    float pit = ((-fv * (float)r) / 384.0f + ch) * D2R;
    float sy = sinf(yaw), cy = cosf(yaw);
    float sp = sinf(pit), cp = cosf(pit);
    float dt = tar[idx], df = fake[idx];
    float px = dt * sy * sp, py = dt * cy * sp, pz = dt * cp;
    float qx = df * sy * sp, qy = df * cy * sp, qz = df * cp;
    A[idx] = make_float4(px, py, pz, 0.5f * (px * px + py * py + pz * pz));
    B[idx] = make_float4(qx, qy, qz, 0.5f * (qx * qx + qy * qy + qz * qz));
    minbuf[idx]         = 0xFFFFFFFFu;   // uint-max (encodes "+inf")
    minbuf[idx + N_PTS] = 0xFFFFFFFFu;
}

// Fused NN, 512x512 wave tiles, 4-tile col strip per wave.
__global__ __launch_bounds__(256, 4) void nn_kernel(
    const float4* __restrict__ A, const float4* __restrict__ B,
    unsigned* __restrict__ rowmin, unsigned* __restrict__ colmin)
{
    int wave = threadIdx.x >> 6;
    int lane = threadIdx.x & 63;
    int jid  = blockIdx.x * 4 + wave;          // 0..20735
    int band = jid / NSTRIP;                   // 0..287
    int strip = jid - band * NSTRIP;           // 0..71
    int rbase = band * TROWS;

    float ax[RI], ay[RI], az[RI], hp[RI], racc[RI];
    #pragma unroll
    for (int k = 0; k < RI; k++) {
        float4 p = A[rbase + k * 64 + lane];   // coalesced
        ax[k] = p.x; ay[k] = p.y; az[k] = p.z; hp[k] = p.w;
        racc[k] = __builtin_inff();
    }

    int nxt = (lane + 1) & 63;

    #pragma unroll 1
    for (int ct = 0; ct < STRIP; ct++) {
        int cbase = strip * (TCOLS * STRIP) + ct * TCOLS;
        float bx[RJ], by[RJ], bz[RJ], hq[RJ], cacc[RJ];
        #pragma unroll
        for (int m = 0; m < RJ; m++) {
            float4 q = B[cbase + m * 64 + lane];
            bx[m] = q.x; by[m] = q.y; bz[m] = q.z; hq[m] = q.w;
            cacc[m] = __builtin_inff();
        }

        #pragma unroll 1
        for (int rr = 0; rr < 64; rr++) {
            #pragma unroll
            for (int k = 0; k < RI; k += 2) {
                #pragma unroll
                for (int m = 0; m < RJ; m += 2) {
                    float t00 = ax[k]   * bx[m]   + ay[k]   * by[m]   + az[k]   * bz[m];
                    float t01 = ax[k]   * bx[m+1] + ay[k]   * by[m+1] + az[k]   * bz[m+1];
                    float t10 = ax[k+1] * bx[m]   + ay[k+1] * by[m]   + az[k+1] * bz[m];
                    float t11 = ax[k+1] * bx[m+1] + ay[k+1] * by[m+1] + az[k+1] * bz[m+1];
                    racc[k]   = min3f(racc[k],   hq[m] - t00, hq[m+1] - t01);
                    racc[k+1] = min3f(racc[k+1], hq[m] - t10, hq[m+1] - t11);
                    cacc[m]   = min3f(cacc[m],   hp[k] - t00, hp[k+1] - t10);
                    cacc[m+1] = min3f(cacc[m+1], hp[k] - t01, hp[k+1] - t11);
                }
            }
            // rotate col block + its accumulators to the previous lane
            #pragma unroll
            for (int m = 0; m < RJ; m++) {
                bx[m]   = __shfl(bx[m],   nxt, 64);
                by[m]   = __shfl(by[m],   nxt, 64);
                bz[m]   = __shfl(bz[m],   nxt, 64);
                hq[m]   = __shfl(hq[m],   nxt, 64);
                cacc[m] = __shfl(cacc[m], nxt, 64);
            }
        }
        #pragma unroll
        for (int m = 0; m < RJ; m++)
            atomicMin(&colmin[cbase + m * 64 + lane], encf(cacc[m]));
    }
    #pragma unroll
    for (int k = 0; k < RI; k++)
        atomicMin(&rowmin[rbase + k * 64 + lane], encf(racc[k]));
}

// sum over i of (hp_i + rowdec_i) + (hq_i + coldec_i), per-block partials
__global__ __launch_bounds__(256) void reduce1(
    const float4* __restrict__ A, const float4* __restrict__ B,
    const unsigned* __restrict__ rowmin, const unsigned* __restrict__ colmin,
    float* __restrict__ partials)
{
    int tid = threadIdx.x;
    int base = blockIdx.x * 1024;
    float s = 0.f;
    #pragma unroll
    for (int t = 0; t < 4; t++) {
        int i = base + t * 256 + tid;
        s += A[i].w + decf(rowmin[i]);
        s += B[i].w + decf(colmin[i]);
    }
    #pragma unroll
    for (int off = 32; off; off >>= 1) s += __shfl_xor(s, off, 64);
    __shared__ float wsum[4];
    if ((tid & 63) == 0) wsum[tid >> 6] = s;
    __syncthreads();
    if (tid == 0) partials[blockIdx.x] = wsum[0] + wsum[1] + wsum[2] + wsum[3];
}

__global__ __launch_bounds__(256) void reduce2(
    const float* __restrict__ partials, float* __restrict__ out)
{
    int tid = threadIdx.x;
    float s = 0.f;
    for (int i = tid; i < 144; i += 256) s += partials[i];
    #pragma unroll
    for (int off = 32; off; off >>= 1) s += __shfl_xor(s, off, 64);
    __shared__ float wsum[4];
    if ((tid & 63) == 0) wsum[tid >> 6] = s;
    __syncthreads();
    if (tid == 0) out[0] = 2.0f * (wsum[0] + wsum[1] + wsum[2] + wsum[3]) / 147456.0f;
}

extern "C" void kernel_launch(void* const* d_in, const int* in_sizes, int n_in,
                              void* d_out, int out_size, void* d_ws, size_t ws_size,
                              hipStream_t stream) {
    const float* fake = (const float*)d_in[0];
    const float* tar  = (const float*)d_in[1];
    const int*   sh_p = (const int*)d_in[2];
    const int*   sw_p = (const int*)d_in[3];
    float* out = (float*)d_out;

    char* ws = (char*)d_ws;
    float4*   A      = (float4*)ws;                                   // P (tar)  [N]
    float4*   Bc     = (float4*)(ws + (size_t)N_PTS * 16);            // Q (fake) [N]
    unsigned* minbuf = (unsigned*)(ws + (size_t)2 * N_PTS * 16);      // rowmin|colmin [2N]
    float*    parts  = (float*)(ws + (size_t)2 * N_PTS * 16 + (size_t)2 * N_PTS * 4);

    prep_kernel<<<(N_PTS + 255) / 256, 256, 0, stream>>>(fake, tar, sh_p, sw_p, A, Bc, minbuf);
    nn_kernel<<<NJOBS / 4, 256, 0, stream>>>(A, Bc, minbuf, minbuf + N_PTS);
    reduce1<<<N_PTS / 1024, 256, 0, stream>>>(A, Bc, minbuf, minbuf + N_PTS, parts);
    reduce2<<<1, 256, 0, stream>>>(parts, out);
}